// Round 1
// baseline (626.136 us; speedup 1.0000x reference)
//
#include <hip/hip_runtime.h>

#define NNODES 50000
#define NEDGES 800000
#define F_IN   128
#define HID    256
#define NOUT   40

// ---------------- CSR build ----------------

__global__ __launch_bounds__(256) void k_degree(const int* __restrict__ dst,
                                                int* __restrict__ count) {
  int e = blockIdx.x * 256 + threadIdx.x;
  if (e < NEDGES) atomicAdd(&count[dst[e]], 1);
}

__global__ __launch_bounds__(256) void k_dinv(const int* __restrict__ count,
                                              float* __restrict__ dinv) {
  int i = blockIdx.x * 256 + threadIdx.x;
  if (i < NNODES) dinv[i] = rsqrtf((float)(count[i] + 1));  // +1 self-loop
}

__global__ __launch_bounds__(1024) void k_scan(const int* __restrict__ count,
                                               int* __restrict__ rowstart) {
  __shared__ int part[1024];
  int t = threadIdx.x;
  const int CH = (NNODES + 1023) / 1024;  // 49
  int beg = t * CH, end = min(beg + CH, NNODES);
  int s = 0;
  for (int i = beg; i < end; i++) s += count[i];
  part[t] = s;
  __syncthreads();
  for (int off = 1; off < 1024; off <<= 1) {
    int v = (t >= off) ? part[t - off] : 0;
    __syncthreads();
    part[t] += v;
    __syncthreads();
  }
  int run = part[t] - s;  // exclusive prefix of this thread's chunk
  for (int i = beg; i < end; i++) { rowstart[i] = run; run += count[i]; }
  if (t == 1023) rowstart[NNODES] = part[1023];
}

__global__ __launch_bounds__(256) void k_scatter(const int* __restrict__ src,
                                                 const int* __restrict__ dst,
                                                 const int* __restrict__ rowstart,
                                                 int* __restrict__ cursor,
                                                 int* __restrict__ csr) {
  int e = blockIdx.x * 256 + threadIdx.x;
  if (e >= NEDGES) return;
  int d = dst[e];
  int p = rowstart[d] + atomicAdd(&cursor[d], 1);
  csr[p] = src[e];
}

// ---------------- gather-based normalized aggregation ----------------
// One wave per dst node; lane holds F/64 contiguous features.
// Y[i] = dinv[i]^2 * X[i] + sum_{edges s->i} dinv[s]*dinv[i]*X[s]

template <int F>
__global__ __launch_bounds__(256) void k_agg(const float* __restrict__ X,
                                             const int* __restrict__ rowstart,
                                             const int* __restrict__ csr,
                                             const float* __restrict__ dinv,
                                             float* __restrict__ Y) {
  constexpr int V = F / 64;  // 2 or 4 floats per lane
  int wave = threadIdx.x >> 6, lane = threadIdx.x & 63;
  int node = blockIdx.x * 4 + wave;
  if (node >= NNODES) return;
  float di = dinv[node];
  float acc[V];
  {
    const float* p = X + (size_t)node * F + lane * V;
    if constexpr (V == 4) {
      float4 v = *reinterpret_cast<const float4*>(p);
      acc[0] = v.x * di * di; acc[1] = v.y * di * di;
      acc[2] = v.z * di * di; acc[3] = v.w * di * di;
    } else {
      float2 v = *reinterpret_cast<const float2*>(p);
      acc[0] = v.x * di * di; acc[1] = v.y * di * di;
    }
  }
  int e = rowstart[node], end = rowstart[node + 1];
  for (; e < end; ++e) {
    int s = csr[e];
    float w = dinv[s] * di;
    const float* p = X + (size_t)s * F + lane * V;
    if constexpr (V == 4) {
      float4 v = *reinterpret_cast<const float4*>(p);
      acc[0] = fmaf(v.x, w, acc[0]); acc[1] = fmaf(v.y, w, acc[1]);
      acc[2] = fmaf(v.z, w, acc[2]); acc[3] = fmaf(v.w, w, acc[3]);
    } else {
      float2 v = *reinterpret_cast<const float2*>(p);
      acc[0] = fmaf(v.x, w, acc[0]); acc[1] = fmaf(v.y, w, acc[1]);
    }
  }
  float* q = Y + (size_t)node * F + lane * V;
  if constexpr (V == 4) {
    float4 v; v.x = acc[0]; v.y = acc[1]; v.z = acc[2]; v.w = acc[3];
    *reinterpret_cast<float4*>(q) = v;
  } else {
    float2 v; v.x = acc[0]; v.y = acc[1];
    *reinterpret_cast<float2*>(q) = v;
  }
}

// ---------------- fp32 tiled GEMM: C = A[MxK] @ B[KxNc] + bias, opt ReLU ----
// BM=64 BN=64 BK=16, 256 threads, 4x4 micro-tile.

template <bool RELU>
__global__ __launch_bounds__(256) void k_gemm(const float* __restrict__ A,
                                              const float* __restrict__ B,
                                              const float* __restrict__ bias,
                                              float* __restrict__ C,
                                              int M, int Nc, int K) {
  __shared__ float As[16][68];  // [k][m], padded for float4-aligned reads
  __shared__ float Bs[16][64];  // [k][n]
  int tid = threadIdx.x;
  int tx = tid & 15, ty = tid >> 4;
  int bm = blockIdx.x * 64;
  int bn = blockIdx.y * 64;
  float acc[4][4] = {};
  int am  = tid >> 2;          // 0..63 A-row within tile
  int ak0 = (tid & 3) * 4;     // 0,4,8,12
  int bk  = tid >> 4;          // 0..15
  int bn0 = (tid & 15) * 4;    // 0..60

  for (int kt = 0; kt < K; kt += 16) {
    {
      int gm = bm + am;
      float4 v = {0.f, 0.f, 0.f, 0.f};
      if (gm < M) v = *reinterpret_cast<const float4*>(A + (size_t)gm * K + kt + ak0);
      As[ak0 + 0][am] = v.x; As[ak0 + 1][am] = v.y;
      As[ak0 + 2][am] = v.z; As[ak0 + 3][am] = v.w;
    }
    {
      int gn = bn + bn0;
      float4 v = {0.f, 0.f, 0.f, 0.f};
      if (gn + 3 < Nc) {
        v = *reinterpret_cast<const float4*>(B + (size_t)(kt + bk) * Nc + gn);
      } else {
        float tmp[4] = {0.f, 0.f, 0.f, 0.f};
        for (int j = 0; j < 4; j++)
          if (gn + j < Nc) tmp[j] = B[(size_t)(kt + bk) * Nc + gn + j];
        v.x = tmp[0]; v.y = tmp[1]; v.z = tmp[2]; v.w = tmp[3];
      }
      *reinterpret_cast<float4*>(&Bs[bk][bn0]) = v;
    }
    __syncthreads();
#pragma unroll
    for (int k = 0; k < 16; k++) {
      float4 a = *reinterpret_cast<const float4*>(&As[k][ty * 4]);
      float4 b = *reinterpret_cast<const float4*>(&Bs[k][tx * 4]);
      float av[4] = {a.x, a.y, a.z, a.w};
      float bv[4] = {b.x, b.y, b.z, b.w};
#pragma unroll
      for (int i = 0; i < 4; i++)
#pragma unroll
        for (int j = 0; j < 4; j++) acc[i][j] = fmaf(av[i], bv[j], acc[i][j]);
    }
    __syncthreads();
  }
#pragma unroll
  for (int i = 0; i < 4; i++) {
    int gm = bm + ty * 4 + i;
    if (gm >= M) continue;
#pragma unroll
    for (int j = 0; j < 4; j++) {
      int gn = bn + tx * 4 + j;
      if (gn >= Nc) continue;
      float v = acc[i][j] + bias[gn];
      if (RELU) v = fmaxf(v, 0.f);
      C[(size_t)gm * Nc + gn] = v;
    }
  }
}

// ---------------- launch ----------------

extern "C" void kernel_launch(void* const* d_in, const int* in_sizes, int n_in,
                              void* d_out, int out_size, void* d_ws, size_t ws_size,
                              hipStream_t stream) {
  (void)in_sizes; (void)n_in; (void)out_size; (void)ws_size;
  const float* x  = (const float*)d_in[0];
  const float* W1 = (const float*)d_in[1];
  const float* b1 = (const float*)d_in[2];
  const float* W2 = (const float*)d_in[3];
  const float* b2 = (const float*)d_in[4];
  const float* Wc = (const float*)d_in[5];
  const float* bc = (const float*)d_in[6];
  const int* edge = (const int*)d_in[7];
  const int* srcE = edge;           // edge_index[0]
  const int* dstE = edge + NEDGES;  // edge_index[1]
  float* out = (float*)d_out;

  char* ws = (char*)d_ws;
  // layout (bytes)
  int*   count    = (int*)(ws + 0);                    // N ints
  int*   cursor   = (int*)(ws + 200000);               // N ints
  int*   rowstart = (int*)(ws + 400000);               // N+1 ints
  float* dinv     = (float*)(ws + 600064);             // N floats
  int*   csr      = (int*)(ws + 800128);               // E ints
  float* aggx     = (float*)(ws + 4000256);            // N*128 f32
  float* h1       = (float*)(ws + 29600256);           // N*256 f32 (later reused for h2)
  float* aggh     = (float*)(ws + 80800256);           // N*256 f32
  // total ≈ 132 MB

  hipMemsetAsync(ws, 0, 400000, stream);  // zero count + cursor

  k_degree<<<(NEDGES + 255) / 256, 256, 0, stream>>>(dstE, count);
  k_dinv<<<(NNODES + 255) / 256, 256, 0, stream>>>(count, dinv);
  k_scan<<<1, 1024, 0, stream>>>(count, rowstart);
  k_scatter<<<(NEDGES + 255) / 256, 256, 0, stream>>>(srcE, dstE, rowstart, cursor, csr);

  // layer 1: agg on 128-dim input, then GEMM+bias+ReLU
  k_agg<F_IN><<<(NNODES + 3) / 4, 256, 0, stream>>>(x, rowstart, csr, dinv, aggx);
  {
    dim3 grid((NNODES + 63) / 64, (HID + 63) / 64);
    k_gemm<true><<<grid, 256, 0, stream>>>(aggx, W1, b1, h1, NNODES, HID, F_IN);
  }
  // layer 2: agg on 256-dim hidden, then GEMM+bias+ReLU (h2 overwrites h1 buffer)
  k_agg<HID><<<(NNODES + 3) / 4, 256, 0, stream>>>(h1, rowstart, csr, dinv, aggh);
  float* h2 = h1;
  {
    dim3 grid((NNODES + 63) / 64, (HID + 63) / 64);
    k_gemm<true><<<grid, 256, 0, stream>>>(aggh, W2, b2, h2, NNODES, HID, HID);
  }
  // classifier
  {
    dim3 grid((NNODES + 63) / 64, (NOUT + 63) / 64);
    k_gemm<false><<<grid, 256, 0, stream>>>(h2, Wc, bc, out, NNODES, NOUT, HID);
  }
}